// Round 9
// baseline (272.882 us; speedup 1.0000x reference)
//
#include <hip/hip_runtime.h>
#include <hip/hip_bf16.h>

typedef unsigned short u16;
typedef __attribute__((ext_vector_type(8))) short short8;
typedef __attribute__((ext_vector_type(4))) float floatx4;

#define N_NODES 50000
#define N_EDGES 400000
#define ET      450000   // edges + self loops
#define F_IN    128
#define C1      256      // H*HID
#define HID     64
#define OUTC    64
#define SLOPE   0.2f

__device__ __forceinline__ float bf2f(u16 v) {
    return __uint_as_float(((unsigned)v) << 16);
}
__device__ __forceinline__ float bflo(unsigned u) { return __uint_as_float(u << 16); }
__device__ __forceinline__ float bfhi(unsigned u) { return __uint_as_float(u & 0xffff0000u); }
__device__ __forceinline__ u16 f2bf(float f) {   // round-to-nearest-even
    unsigned u = __float_as_uint(f);
    return (u16)((u + 0x7fffu + ((u >> 16) & 1u)) >> 16);
}
__device__ __forceinline__ unsigned pack2(float a, float b) {
    return (unsigned)f2bf(a) | ((unsigned)f2bf(b) << 16);
}
// single-instruction cross-lane add via DPP (no LDS, no lgkm wait)
template<int CTRL>
__device__ __forceinline__ float dpp_add(float x) {
    return x + __int_as_float(__builtin_amdgcn_update_dpp(
        0, __float_as_int(x), CTRL, 0xF, 0xF, true));
}
__device__ __forceinline__ void unpack8(uint4 u, float* f) {
    f[0] = bflo(u.x); f[1] = bfhi(u.x);
    f[2] = bflo(u.y); f[3] = bfhi(u.y);
    f[4] = bflo(u.z); f[5] = bfhi(u.z);
    f[6] = bflo(u.w); f[7] = bfhi(u.w);
}

// ---------------- dtype detector (f32 vs bf16 input buffers) ----------------
__global__ __launch_bounds__(256) void detect_kernel(const unsigned* __restrict__ xw,
                                                     int* __restrict__ cnt)
{
    unsigned w = xw[threadIdx.x];
    unsigned aexp = (w >> 7) & 0xFFu;   // exponent field of low-half bf16
    if (aexp >= 170u || aexp <= 40u) atomicAdd(cnt, 1);
}

// ---------------- fused param convert --------------------------------------
__global__ __launch_bounds__(256) void convert_all_kernel(
    const void* wl1, const void* wr1, const void* wl2, const void* wr2,
    const void* s0, const void* s1, const void* s2, const void* s3,
    const void* s4, const void* s5, const void* s6, const void* s7,
    u16* __restrict__ wt, u16* __restrict__ prm, const int* __restrict__ cnt)
{
    bool f32m = (*cnt >= 32);
    if (blockIdx.x == 384) {
        for (int t = threadIdx.x; t < 1280; t += 256) {
            const void* src; int local;
            if      (t < 256)  { src = s0; local = t; }
            else if (t < 512)  { src = s1; local = t - 256; }
            else if (t < 768)  { src = s2; local = t - 512; }
            else if (t < 1024) { src = s3; local = t - 768; }
            else if (t < 1088) { src = s4; local = t - 1024; }
            else if (t < 1152) { src = s5; local = t - 1088; }
            else if (t < 1216) { src = s6; local = t - 1152; }
            else               { src = s7; local = t - 1216; }
            prm[t] = f32m ? f2bf(((const float*)src)[local]) : ((const u16*)src)[local];
        }
        return;
    }
    int t = blockIdx.x * 256 + threadIdx.x;   // 98304 total
    const void* src; int local, k, n, K, base;
    if (t < 32768)      { src = wl1; local = t;         k = local >> 8; n = local & 255; K = 128; base = 0; }
    else if (t < 65536) { src = wr1; local = t - 32768; k = local >> 8; n = local & 255; K = 128; base = 32768; }
    else if (t < 81920) { src = wl2; local = t - 65536; k = local >> 6; n = local & 63;  K = 256; base = 65536; }
    else                { src = wr2; local = t - 81920; k = local >> 6; n = local & 63;  K = 256; base = 81920; }
    u16 v = f32m ? f2bf(((const float*)src)[local]) : ((const u16*)src)[local];
    wt[base + n * K + k] = v;
}

// ---------------- CSR build (by dst) ----------------
__global__ __launch_bounds__(256) void hist_kernel(const int* __restrict__ ei,
                                                   int* __restrict__ hist)
{
    int t = blockIdx.x * 256 + threadIdx.x;
    if (t >= ET) return;
    int d = (t < N_EDGES) ? ei[N_EDGES + t] : t - N_EDGES;
    atomicAdd(&hist[d], 1);
}

__global__ __launch_bounds__(256) void scan1_kernel(const int* __restrict__ hist,
                                                    int* __restrict__ rowptr,
                                                    int* __restrict__ bsum)
{
    int t = threadIdx.x;
    int i = blockIdx.x * 256 + t;
    int v = (i < N_NODES) ? hist[i] : 0;
    __shared__ int sd[256];
    sd[t] = v;
    __syncthreads();
    #pragma unroll
    for (int ofs = 1; ofs < 256; ofs <<= 1) {
        int u = (t >= ofs) ? sd[t - ofs] : 0;
        __syncthreads();
        sd[t] += u;
        __syncthreads();
    }
    if (i < N_NODES) rowptr[i] = sd[t] - v;
    if (t == 255) bsum[blockIdx.x] = sd[255];
}

__global__ __launch_bounds__(256) void scan2_kernel(int* __restrict__ bsum,
                                                    int* __restrict__ boff)
{
    int t = threadIdx.x;
    int v = (t < 196) ? bsum[t] : 0;
    __shared__ int sd[256];
    sd[t] = v;
    __syncthreads();
    #pragma unroll
    for (int ofs = 1; ofs < 256; ofs <<= 1) {
        int u = (t >= ofs) ? sd[t - ofs] : 0;
        __syncthreads();
        sd[t] += u;
        __syncthreads();
    }
    if (t < 196) boff[t] = sd[t] - v;
}

__global__ __launch_bounds__(256) void scan3_kernel(int* __restrict__ rowptr,
                                                    const int* __restrict__ boff,
                                                    int* __restrict__ off)
{
    int i = blockIdx.x * 256 + threadIdx.x;
    if (i >= N_NODES) return;
    int r = rowptr[i] + boff[blockIdx.x];
    rowptr[i] = r;
    off[i] = r;
}

__global__ __launch_bounds__(256) void scatter_kernel(const int* __restrict__ ei,
                                                      int* __restrict__ off,
                                                      int* __restrict__ src_csr)
{
    int t = blockIdx.x * 256 + threadIdx.x;
    if (t >= ET) return;
    int s, d;
    if (t < N_EDGES) { s = ei[t]; d = ei[N_EDGES + t]; } else { s = d = t - N_EDGES; }
    int pos = atomicAdd(&off[d], 1);
    src_csr[pos] = s;
}

// ---------------- fused layer-1 linear: xl1 AND xr1 from one X staging ------
__global__ __launch_bounds__(256) void lin1_fused_kernel(
    const u16* __restrict__ X, const u16* __restrict__ Wt,   // Wt: [2][256][128]
    const u16* __restrict__ bl, const u16* __restrict__ br,
    u16* __restrict__ Yl, u16* __restrict__ Yr, int nrows,
    const int* __restrict__ cnt)
{
    constexpr int K = 128, N = 256, LS = K + 8;
    __shared__ __align__(16) u16 sX[64 * LS];
    __shared__ __align__(16) u16 sW[64 * LS];
    const bool f32m = (*cnt >= 32);
    const float* X32 = (const float*)X;
    const int row0 = blockIdx.x * 64;
    const int wave = threadIdx.x >> 6, lane = threadIdx.x & 63;
    const int quad = lane >> 4, l16 = lane & 15;

    for (int i = threadIdx.x * 8; i < 64 * K; i += 2048) {
        int r = i >> 7, c = i & 127;
        int gr = row0 + r;
        u16* dst = &sX[r * LS + c];
        if (f32m) {
            float4 v0 = make_float4(0.f, 0.f, 0.f, 0.f), v1 = v0;
            if (gr < nrows) {
                v0 = *(const float4*)&X32[(size_t)gr * K + c];
                v1 = *(const float4*)&X32[(size_t)gr * K + c + 4];
            }
            ushort4 p0, p1;
            p0.x = f2bf(v0.x); p0.y = f2bf(v0.y); p0.z = f2bf(v0.z); p0.w = f2bf(v0.w);
            p1.x = f2bf(v1.x); p1.y = f2bf(v1.y); p1.z = f2bf(v1.z); p1.w = f2bf(v1.w);
            *(ushort4*)dst = p0;
            *(ushort4*)(dst + 4) = p1;
        } else {
            uint4 v = {0u, 0u, 0u, 0u};
            if (gr < nrows) v = *(const uint4*)&X[(size_t)gr * K + c];
            *(uint4*)dst = v;
        }
    }

    for (int side = 0; side < 2; ++side) {
        const u16* wbase = Wt + side * (N * K);
        const u16* bias  = side ? br : bl;
        u16* Y = side ? Yr : Yl;
        for (int ch = 0; ch < 4; ++ch) {
            __syncthreads();
            for (int i = threadIdx.x * 8; i < 64 * K; i += 2048) {
                int n = i >> 7, c = i & 127;
                *(uint4*)&sW[n * LS + c] = *(const uint4*)&wbase[(size_t)(ch * 64 + n) * K + c];
            }
            __syncthreads();
            floatx4 acc0 = {0.f, 0.f, 0.f, 0.f}, acc1 = acc0, acc2 = acc0, acc3 = acc0;
            #pragma unroll
            for (int kk = 0; kk < 4; ++kk) {
                short8 a  = *(const short8*)&sX[(wave * 16 + l16) * LS + kk * 32 + quad * 8];
                short8 b0 = *(const short8*)&sW[(l16) * LS + kk * 32 + quad * 8];
                short8 b1 = *(const short8*)&sW[(16 + l16) * LS + kk * 32 + quad * 8];
                short8 b2 = *(const short8*)&sW[(32 + l16) * LS + kk * 32 + quad * 8];
                short8 b3 = *(const short8*)&sW[(48 + l16) * LS + kk * 32 + quad * 8];
                acc0 = __builtin_amdgcn_mfma_f32_16x16x32_bf16(a, b0, acc0, 0, 0, 0);
                acc1 = __builtin_amdgcn_mfma_f32_16x16x32_bf16(a, b1, acc1, 0, 0, 0);
                acc2 = __builtin_amdgcn_mfma_f32_16x16x32_bf16(a, b2, acc2, 0, 0, 0);
                acc3 = __builtin_amdgcn_mfma_f32_16x16x32_bf16(a, b3, acc3, 0, 0, 0);
            }
            const int rbase = row0 + wave * 16 + quad * 4;
            #pragma unroll
            for (int cf = 0; cf < 4; ++cf) {
                const floatx4 av = (cf == 0) ? acc0 : (cf == 1) ? acc1 : (cf == 2) ? acc2 : acc3;
                const int col = ch * 64 + cf * 16 + l16;
                const float bv = bf2f(bias[col]);
                #pragma unroll
                for (int r = 0; r < 4; ++r) {
                    int row = rbase + r;
                    if (row < nrows) Y[(size_t)row * N + col] = f2bf(av[r] + bv);
                }
            }
        }
    }
}

// ---------------- fused layer-2 linear ------------------------------------
__global__ __launch_bounds__(256) void lin2_fused_kernel(
    const u16* __restrict__ X, const u16* __restrict__ Wt,   // Wt: [2][64][256]
    const u16* __restrict__ bl, const u16* __restrict__ br,
    u16* __restrict__ Yl, u16* __restrict__ Yr, int nrows)
{
    constexpr int K = 256, N = 64, LS = K + 8;
    __shared__ __align__(16) u16 sX[64 * LS];
    __shared__ __align__(16) u16 sW[64 * LS];
    const int row0 = blockIdx.x * 64;
    const int wave = threadIdx.x >> 6, lane = threadIdx.x & 63;
    const int quad = lane >> 4, l16 = lane & 15;

    for (int i = threadIdx.x * 8; i < 64 * K; i += 2048) {
        int r = i >> 8, c = i & 255;
        int gr = row0 + r;
        uint4 v = {0u, 0u, 0u, 0u};
        if (gr < nrows) v = *(const uint4*)&X[(size_t)gr * K + c];
        *(uint4*)&sX[r * LS + c] = v;
    }

    for (int side = 0; side < 2; ++side) {
        const u16* wbase = Wt + side * (N * K);
        const u16* bias  = side ? br : bl;
        u16* Y = side ? Yr : Yl;
        __syncthreads();
        for (int i = threadIdx.x * 8; i < 64 * K; i += 2048) {
            int n = i >> 8, c = i & 255;
            *(uint4*)&sW[n * LS + c] = *(const uint4*)&wbase[(size_t)n * K + c];
        }
        __syncthreads();
        floatx4 acc0 = {0.f, 0.f, 0.f, 0.f}, acc1 = acc0, acc2 = acc0, acc3 = acc0;
        #pragma unroll
        for (int kk = 0; kk < 8; ++kk) {
            short8 a  = *(const short8*)&sX[(wave * 16 + l16) * LS + kk * 32 + quad * 8];
            short8 b0 = *(const short8*)&sW[(l16) * LS + kk * 32 + quad * 8];
            short8 b1 = *(const short8*)&sW[(16 + l16) * LS + kk * 32 + quad * 8];
            short8 b2 = *(const short8*)&sW[(32 + l16) * LS + kk * 32 + quad * 8];
            short8 b3 = *(const short8*)&sW[(48 + l16) * LS + kk * 32 + quad * 8];
            acc0 = __builtin_amdgcn_mfma_f32_16x16x32_bf16(a, b0, acc0, 0, 0, 0);
            acc1 = __builtin_amdgcn_mfma_f32_16x16x32_bf16(a, b1, acc1, 0, 0, 0);
            acc2 = __builtin_amdgcn_mfma_f32_16x16x32_bf16(a, b2, acc2, 0, 0, 0);
            acc3 = __builtin_amdgcn_mfma_f32_16x16x32_bf16(a, b3, acc3, 0, 0, 0);
        }
        const int rbase = row0 + wave * 16 + quad * 4;
        #pragma unroll
        for (int cf = 0; cf < 4; ++cf) {
            const floatx4 av = (cf == 0) ? acc0 : (cf == 1) ? acc1 : (cf == 2) ? acc2 : acc3;
            const int col = cf * 16 + l16;
            const float bv = bf2f(bias[col]);
            #pragma unroll
            for (int r = 0; r < 4; ++r) {
                int row = rbase + r;
                if (row < nrows) Y[(size_t)row * N + col] = f2bf(av[r] + bv);
            }
        }
    }
}

// ---------------- layer 1 fused per-node GATv2 (4 heads x 64 ch) ------------
// one wave per node; lane layout: half = l>>5, q = l&31 covers channels
// [8q, 8q+8) (head = q>>3). Half-wave processes 2 edges/iter (4 per wave).
// Head-reduce over 8 lanes = 3 DPP stages (no LDS, no waits). Cross-half
// online-softmax merge once at the end.
__global__ __launch_bounds__(256) void node1_kernel(
    const u16* __restrict__ xl, const u16* __restrict__ xr,
    const int* __restrict__ rowptr, const int* __restrict__ hist,
    const int* __restrict__ src_csr, const u16* __restrict__ att,
    const u16* __restrict__ bias, u16* __restrict__ hout)
{
    const int d = __builtin_amdgcn_readfirstlane(blockIdx.x * 4 + (threadIdx.x >> 6));
    if (d >= N_NODES) return;
    const int l = threadIdx.x & 63;
    const int half = l >> 5, q = l & 31;
    const int c0 = q * 8;
    const int start = rowptr[d];
    const int deg = hist[d];

    float at[8], rr[8];
    unpack8(*(const uint4*)&att[c0], at);
    unpack8(*(const uint4*)&xr[(size_t)d * C1 + c0], rr);

    float m = -1e30f, la = 0.f;
    float acc[8] = {0.f, 0.f, 0.f, 0.f, 0.f, 0.f, 0.f, 0.f};
    for (int j = 0; j < deg; j += 4) {
        const int jj0 = j + half * 2;
        const bool vA = jj0 < deg, vB = jj0 + 1 < deg;
        int sA = vA ? src_csr[start + jj0] : d;
        int sB = vB ? src_csr[start + jj0 + 1] : d;
        float xa[8], xb[8];
        unpack8(*(const uint4*)&xl[(size_t)sA * C1 + c0], xa);
        unpack8(*(const uint4*)&xl[(size_t)sB * C1 + c0], xb);
        float pA = 0.f, pB = 0.f, t;
        #pragma unroll
        for (int c = 0; c < 8; ++c) {
            t = xa[c] + rr[c]; t = t > 0.f ? t : SLOPE * t; pA += t * at[c];
            t = xb[c] + rr[c]; t = t > 0.f ? t : SLOPE * t; pB += t * at[c];
        }
        // reduce over the 8 sub-lanes of this head
        pA = dpp_add<0xB1>(pA);  pB = dpp_add<0xB1>(pB);    // xor 1 (quad_perm 1,0,3,2)
        pA = dpp_add<0x4E>(pA);  pB = dpp_add<0x4E>(pB);    // xor 2 (quad_perm 2,3,0,1)
        pA = dpp_add<0x141>(pA); pB = dpp_add<0x141>(pB);   // row_half_mirror (cross-quad in 8)
        float pAv = vA ? pA : -1e30f;
        float pBv = vB ? pB : -1e30f;
        float mn = fmaxf(m, fmaxf(pAv, pBv));
        float sc = __expf(m - mn);
        float wA = vA ? __expf(pA - mn) : 0.f;
        float wB = vB ? __expf(pB - mn) : 0.f;
        la = la * sc + wA + wB;
        #pragma unroll
        for (int c = 0; c < 8; ++c)
            acc[c] = acc[c] * sc + wA * xa[c] + wB * xb[c];
        m = mn;
    }
    // merge the two half-waves' states (xor 32)
    {
        float mo = __shfl_xor(m, 32);
        float lo = __shfl_xor(la, 32);
        float mn = fmaxf(m, mo);
        float s0 = __expf(m - mn), s1 = __expf(mo - mn);
        la = la * s0 + lo * s1;
        #pragma unroll
        for (int c = 0; c < 8; ++c) {
            float bo = __shfl_xor(acc[c], 32);
            acc[c] = acc[c] * s0 + bo * s1;
        }
    }
    if (half == 0) {
        const float inv = 1.f / la;
        float bv[8];
        unpack8(*(const uint4*)&bias[c0], bv);
        float v[8];
        #pragma unroll
        for (int c = 0; c < 8; ++c) {
            float x = acc[c] * inv + bv[c];
            v[c] = x > 0.f ? x : __expf(fminf(x, 0.f)) - 1.f;
        }
        uint4 o;
        o.x = pack2(v[0], v[1]); o.y = pack2(v[2], v[3]);
        o.z = pack2(v[4], v[5]); o.w = pack2(v[6], v[7]);
        *(uint4*)&hout[(size_t)d * C1 + c0] = o;
    }
}

// ---------------- layer 2 fused per-node GATv2 (1 head x 64 ch) --------------
// wave = 4x 16-lane groups, group g handles edge j+g; group reduce via DPP.
__global__ __launch_bounds__(256) void node2_kernel(
    const u16* __restrict__ xl, const u16* __restrict__ xr,
    const int* __restrict__ rowptr, const int* __restrict__ hist,
    const int* __restrict__ src_csr, const u16* __restrict__ att,
    const u16* __restrict__ bias, void* __restrict__ outp,
    const int* __restrict__ cnt)
{
    const int d = __builtin_amdgcn_readfirstlane(blockIdx.x * 4 + (threadIdx.x >> 6));
    if (d >= N_NODES) return;
    const int l = threadIdx.x & 63;
    const int start = rowptr[d];
    const int deg = hist[d];
    const int g = l >> 4, sub = l & 15;
    const int c0 = sub * 4;

    ushort4 av = *(const ushort4*)&att[c0];
    const float at0 = bf2f(av.x), at1 = bf2f(av.y), at2 = bf2f(av.z), at3 = bf2f(av.w);
    ushort4 rv = *(const ushort4*)&xr[(size_t)d * OUTC + c0];
    const float r0 = bf2f(rv.x), r1 = bf2f(rv.y), r2 = bf2f(rv.z), r3 = bf2f(rv.w);

    float m = -1e30f, la = 0.f;
    float a0 = 0.f, a1 = 0.f, a2 = 0.f, a3 = 0.f;
    for (int j = 0; j < deg; j += 4) {
        const bool valid = j + g < deg;
        int s = valid ? src_csr[start + j + g] : d;
        ushort4 xv = *(const ushort4*)&xl[(size_t)s * OUTC + c0];
        float x0 = bf2f(xv.x), x1 = bf2f(xv.y), x2 = bf2f(xv.z), x3 = bf2f(xv.w);
        float t, p = 0.f;
        t = x0 + r0; t = t > 0.f ? t : SLOPE * t; p += t * at0;
        t = x1 + r1; t = t > 0.f ? t : SLOPE * t; p += t * at1;
        t = x2 + r2; t = t > 0.f ? t : SLOPE * t; p += t * at2;
        t = x3 + r3; t = t > 0.f ? t : SLOPE * t; p += t * at3;
        p = dpp_add<0xB1>(p);    // xor 1
        p = dpp_add<0x4E>(p);    // xor 2
        p = dpp_add<0x141>(p);   // cross-quad within 8
        p = dpp_add<0x140>(p);   // row_mirror: cross-8 within 16
        float pv = valid ? p : -1e30f;
        float mn = fmaxf(m, pv);
        float sc = __expf(m - mn);
        float w  = valid ? __expf(p - mn) : 0.f;
        la = la * sc + w;
        a0 = a0 * sc + w * x0;
        a1 = a1 * sc + w * x1;
        a2 = a2 * sc + w * x2;
        a3 = a3 * sc + w * x3;
        m = mn;
    }
    // merge the 4 groups' online-softmax states (xor 16, then 32)
    #pragma unroll
    for (int ofs = 16; ofs <= 32; ofs <<= 1) {
        float mo = __shfl_xor(m, ofs);
        float lo = __shfl_xor(la, ofs);
        float b0 = __shfl_xor(a0, ofs);
        float b1 = __shfl_xor(a1, ofs);
        float b2 = __shfl_xor(a2, ofs);
        float b3 = __shfl_xor(a3, ofs);
        float mn = fmaxf(m, mo);
        float s0 = __expf(m - mn), s1 = __expf(mo - mn);
        la = la * s0 + lo * s1;
        a0 = a0 * s0 + b0 * s1;
        a1 = a1 * s0 + b1 * s1;
        a2 = a2 * s0 + b2 * s1;
        a3 = a3 * s0 + b3 * s1;
        m = mn;
    }
    if (g == 0) {
        const float inv = 1.f / la;
        float v0 = a0 * inv + bf2f(bias[c0 + 0]);
        float v1 = a1 * inv + bf2f(bias[c0 + 1]);
        float v2 = a2 * inv + bf2f(bias[c0 + 2]);
        float v3 = a3 * inv + bf2f(bias[c0 + 3]);
        if (*cnt >= 32) {
            float4 o = make_float4(v0, v1, v2, v3);
            *(float4*)&((float*)outp)[(size_t)d * OUTC + c0] = o;
        } else {
            ushort4 o;
            o.x = f2bf(v0); o.y = f2bf(v1); o.z = f2bf(v2); o.w = f2bf(v3);
            *(ushort4*)&((u16*)outp)[(size_t)d * OUTC + c0] = o;
        }
    }
}

extern "C" void kernel_launch(void* const* d_in, const int* in_sizes, int n_in,
                              void* d_out, int out_size, void* d_ws, size_t ws_size,
                              hipStream_t stream)
{
    const void* x  = d_in[0];
    const int*  ei = (const int*)d_in[1];

    char* ws = (char*)d_ws;
    u16* xl1     = (u16*)(ws + 0);          // 25.6 MB
    u16* xr1     = (u16*)(ws + 25600000);   // 25.6 MB
    u16* hbuf    = (u16*)(ws + 51200000);   // 25.6 MB
    u16* xl2     = (u16*)(ws + 0);          // overlay xl1 (dead after node1)
    u16* xr2     = (u16*)(ws + 6400000);
    int* hist    = (int*)(ws + 76800000);
    int* rowptr  = (int*)(ws + 77000000);
    int* off     = (int*)(ws + 77200000);
    int* src_csr = (int*)(ws + 77400000);   // 1.8 MB
    int* cnt     = (int*)(ws + 79200000);
    u16* prm     = (u16*)(ws + 79200064);   // 1280 u16 small params
    u16* wt      = (u16*)(ws + 79210240);   // 98304 u16 transposed weights
    int* bsum    = (int*)(ws + 79410000);
    int* boff    = (int*)(ws + 79411024);

    u16* bl1   = prm + 0;
    u16* br1   = prm + 256;
    u16* att1  = prm + 512;
    u16* bias1 = prm + 768;
    u16* bl2   = prm + 1024;
    u16* br2   = prm + 1088;
    u16* att2  = prm + 1152;
    u16* bias2 = prm + 1216;
    u16* wt1   = wt + 0;       // [2][256][128]
    u16* wt2   = wt + 65536;   // [2][64][256]

    hipMemsetAsync(cnt, 0, 4, stream);
    detect_kernel<<<1, 256, 0, stream>>>((const unsigned*)x, cnt);
    convert_all_kernel<<<385, 256, 0, stream>>>(
        d_in[2], d_in[4], d_in[8], d_in[10],
        d_in[3], d_in[5], d_in[6], d_in[7], d_in[9], d_in[11], d_in[12], d_in[13],
        wt, prm, cnt);

    hipMemsetAsync(hist, 0, 200000, stream);
    const int eb = (ET + 255) / 256;
    hist_kernel<<<eb, 256, 0, stream>>>(ei, hist);
    scan1_kernel<<<196, 256, 0, stream>>>(hist, rowptr, bsum);
    scan2_kernel<<<1, 256, 0, stream>>>(bsum, boff);
    scan3_kernel<<<196, 256, 0, stream>>>(rowptr, boff, off);
    scatter_kernel<<<eb, 256, 0, stream>>>(ei, off, src_csr);

    const int gb = (N_NODES + 63) / 64;   // 782
    lin1_fused_kernel<<<gb, 256, 0, stream>>>((const u16*)x, wt1, bl1, br1, xl1, xr1, N_NODES, cnt);
    const int nb = (N_NODES * 64 + 255) / 256;   // 12500 blocks, 4 waves each
    node1_kernel<<<nb, 256, 0, stream>>>(xl1, xr1, rowptr, hist, src_csr, att1, bias1, hbuf);

    lin2_fused_kernel<<<gb, 256, 0, stream>>>(hbuf, wt2, bl2, br2, xl2, xr2, N_NODES);
    node2_kernel<<<nb, 256, 0, stream>>>(xl2, xr2, rowptr, hist, src_csr, att2, bias2, d_out, cnt);
}

// Round 10
// 262.034 us; speedup vs baseline: 1.0414x; 1.0414x over previous
//
#include <hip/hip_runtime.h>
#include <hip/hip_bf16.h>

typedef unsigned short u16;
typedef __attribute__((ext_vector_type(8))) short short8;
typedef __attribute__((ext_vector_type(4))) float floatx4;
typedef __attribute__((ext_vector_type(2))) float f32x2;

#define N_NODES 50000
#define N_EDGES 400000
#define ET      450000   // edges + self loops
#define F_IN    128
#define C1      256      // H*HID
#define HID     64
#define OUTC    64
#define SLOPE   0.2f

__device__ __forceinline__ float bf2f(u16 v) {
    return __uint_as_float(((unsigned)v) << 16);
}
__device__ __forceinline__ float bflo(unsigned u) { return __uint_as_float(u << 16); }
__device__ __forceinline__ float bfhi(unsigned u) { return __uint_as_float(u & 0xffff0000u); }
__device__ __forceinline__ u16 f2bf(float f) {   // round-to-nearest-even
    unsigned u = __float_as_uint(f);
    return (u16)((u + 0x7fffu + ((u >> 16) & 1u)) >> 16);
}
__device__ __forceinline__ f32x2 up2(unsigned u) {
    f32x2 r; r.x = bflo(u); r.y = bfhi(u); return r;
}
// single-instruction cross-lane add via DPP (no LDS, no lgkm wait)
template<int CTRL>
__device__ __forceinline__ float dpp_add(float x) {
    return x + __int_as_float(__builtin_amdgcn_update_dpp(
        0, __float_as_int(x), CTRL, 0xF, 0xF, true));
}
// reduce over 16-lane group: xor1, xor2, mirror-8, mirror-16
__device__ __forceinline__ float red16(float p) {
    p = dpp_add<0xB1>(p);
    p = dpp_add<0x4E>(p);
    p = dpp_add<0x141>(p);
    p = dpp_add<0x140>(p);
    return p;
}

// ---------------- dtype detector (f32 vs bf16 input buffers) ----------------
__global__ __launch_bounds__(256) void detect_kernel(const unsigned* __restrict__ xw,
                                                     int* __restrict__ cnt)
{
    unsigned w = xw[threadIdx.x];
    unsigned aexp = (w >> 7) & 0xFFu;   // exponent field of low-half bf16
    if (aexp >= 170u || aexp <= 40u) atomicAdd(cnt, 1);
}

// ---------------- fused param convert --------------------------------------
__global__ __launch_bounds__(256) void convert_all_kernel(
    const void* wl1, const void* wr1, const void* wl2, const void* wr2,
    const void* s0, const void* s1, const void* s2, const void* s3,
    const void* s4, const void* s5, const void* s6, const void* s7,
    u16* __restrict__ wt, u16* __restrict__ prm, const int* __restrict__ cnt)
{
    bool f32m = (*cnt >= 32);
    if (blockIdx.x == 384) {
        for (int t = threadIdx.x; t < 1280; t += 256) {
            const void* src; int local;
            if      (t < 256)  { src = s0; local = t; }
            else if (t < 512)  { src = s1; local = t - 256; }
            else if (t < 768)  { src = s2; local = t - 512; }
            else if (t < 1024) { src = s3; local = t - 768; }
            else if (t < 1088) { src = s4; local = t - 1024; }
            else if (t < 1152) { src = s5; local = t - 1088; }
            else if (t < 1216) { src = s6; local = t - 1152; }
            else               { src = s7; local = t - 1216; }
            prm[t] = f32m ? f2bf(((const float*)src)[local]) : ((const u16*)src)[local];
        }
        return;
    }
    int t = blockIdx.x * 256 + threadIdx.x;   // 98304 total
    const void* src; int local, k, n, K, base;
    if (t < 32768)      { src = wl1; local = t;         k = local >> 8; n = local & 255; K = 128; base = 0; }
    else if (t < 65536) { src = wr1; local = t - 32768; k = local >> 8; n = local & 255; K = 128; base = 32768; }
    else if (t < 81920) { src = wl2; local = t - 65536; k = local >> 6; n = local & 63;  K = 256; base = 65536; }
    else                { src = wr2; local = t - 81920; k = local >> 6; n = local & 63;  K = 256; base = 81920; }
    u16 v = f32m ? f2bf(((const float*)src)[local]) : ((const u16*)src)[local];
    wt[base + n * K + k] = v;
}

// ---------------- CSR build (by dst) ----------------
__global__ __launch_bounds__(256) void hist_kernel(const int* __restrict__ ei,
                                                   int* __restrict__ hist)
{
    int t = blockIdx.x * 256 + threadIdx.x;
    if (t >= ET) return;
    int d = (t < N_EDGES) ? ei[N_EDGES + t] : t - N_EDGES;
    atomicAdd(&hist[d], 1);
}

__global__ __launch_bounds__(256) void scan1_kernel(const int* __restrict__ hist,
                                                    int* __restrict__ rowptr,
                                                    int* __restrict__ bsum)
{
    int t = threadIdx.x;
    int i = blockIdx.x * 256 + t;
    int v = (i < N_NODES) ? hist[i] : 0;
    __shared__ int sd[256];
    sd[t] = v;
    __syncthreads();
    #pragma unroll
    for (int ofs = 1; ofs < 256; ofs <<= 1) {
        int u = (t >= ofs) ? sd[t - ofs] : 0;
        __syncthreads();
        sd[t] += u;
        __syncthreads();
    }
    if (i < N_NODES) rowptr[i] = sd[t] - v;
    if (t == 255) bsum[blockIdx.x] = sd[255];
}

__global__ __launch_bounds__(256) void scan2_kernel(int* __restrict__ bsum,
                                                    int* __restrict__ boff)
{
    int t = threadIdx.x;
    int v = (t < 196) ? bsum[t] : 0;
    __shared__ int sd[256];
    sd[t] = v;
    __syncthreads();
    #pragma unroll
    for (int ofs = 1; ofs < 256; ofs <<= 1) {
        int u = (t >= ofs) ? sd[t - ofs] : 0;
        __syncthreads();
        sd[t] += u;
        __syncthreads();
    }
    if (t < 196) boff[t] = sd[t] - v;
}

__global__ __launch_bounds__(256) void scan3_kernel(int* __restrict__ rowptr,
                                                    const int* __restrict__ boff,
                                                    int* __restrict__ off)
{
    int i = blockIdx.x * 256 + threadIdx.x;
    if (i >= N_NODES) return;
    int r = rowptr[i] + boff[blockIdx.x];
    rowptr[i] = r;
    off[i] = r;
}

__global__ __launch_bounds__(256) void scatter_kernel(const int* __restrict__ ei,
                                                      int* __restrict__ off,
                                                      int* __restrict__ src_csr)
{
    int t = blockIdx.x * 256 + threadIdx.x;
    if (t >= ET) return;
    int s, d;
    if (t < N_EDGES) { s = ei[t]; d = ei[N_EDGES + t]; } else { s = d = t - N_EDGES; }
    int pos = atomicAdd(&off[d], 1);
    src_csr[pos] = s;
}

// ---------------- fused layer-1 linear: xl1 AND xr1 from one X staging ------
__global__ __launch_bounds__(256) void lin1_fused_kernel(
    const u16* __restrict__ X, const u16* __restrict__ Wt,   // Wt: [2][256][128]
    const u16* __restrict__ bl, const u16* __restrict__ br,
    u16* __restrict__ Yl, u16* __restrict__ Yr, int nrows,
    const int* __restrict__ cnt)
{
    constexpr int K = 128, N = 256, LS = K + 8;
    __shared__ __align__(16) u16 sX[64 * LS];
    __shared__ __align__(16) u16 sW[64 * LS];
    const bool f32m = (*cnt >= 32);
    const float* X32 = (const float*)X;
    const int row0 = blockIdx.x * 64;
    const int wave = threadIdx.x >> 6, lane = threadIdx.x & 63;
    const int quad = lane >> 4, l16 = lane & 15;

    for (int i = threadIdx.x * 8; i < 64 * K; i += 2048) {
        int r = i >> 7, c = i & 127;
        int gr = row0 + r;
        u16* dst = &sX[r * LS + c];
        if (f32m) {
            float4 v0 = make_float4(0.f, 0.f, 0.f, 0.f), v1 = v0;
            if (gr < nrows) {
                v0 = *(const float4*)&X32[(size_t)gr * K + c];
                v1 = *(const float4*)&X32[(size_t)gr * K + c + 4];
            }
            ushort4 p0, p1;
            p0.x = f2bf(v0.x); p0.y = f2bf(v0.y); p0.z = f2bf(v0.z); p0.w = f2bf(v0.w);
            p1.x = f2bf(v1.x); p1.y = f2bf(v1.y); p1.z = f2bf(v1.z); p1.w = f2bf(v1.w);
            *(ushort4*)dst = p0;
            *(ushort4*)(dst + 4) = p1;
        } else {
            uint4 v = {0u, 0u, 0u, 0u};
            if (gr < nrows) v = *(const uint4*)&X[(size_t)gr * K + c];
            *(uint4*)dst = v;
        }
    }

    for (int side = 0; side < 2; ++side) {
        const u16* wbase = Wt + side * (N * K);
        const u16* bias  = side ? br : bl;
        u16* Y = side ? Yr : Yl;
        for (int ch = 0; ch < 4; ++ch) {
            __syncthreads();
            for (int i = threadIdx.x * 8; i < 64 * K; i += 2048) {
                int n = i >> 7, c = i & 127;
                *(uint4*)&sW[n * LS + c] = *(const uint4*)&wbase[(size_t)(ch * 64 + n) * K + c];
            }
            __syncthreads();
            floatx4 acc0 = {0.f, 0.f, 0.f, 0.f}, acc1 = acc0, acc2 = acc0, acc3 = acc0;
            #pragma unroll
            for (int kk = 0; kk < 4; ++kk) {
                short8 a  = *(const short8*)&sX[(wave * 16 + l16) * LS + kk * 32 + quad * 8];
                short8 b0 = *(const short8*)&sW[(l16) * LS + kk * 32 + quad * 8];
                short8 b1 = *(const short8*)&sW[(16 + l16) * LS + kk * 32 + quad * 8];
                short8 b2 = *(const short8*)&sW[(32 + l16) * LS + kk * 32 + quad * 8];
                short8 b3 = *(const short8*)&sW[(48 + l16) * LS + kk * 32 + quad * 8];
                acc0 = __builtin_amdgcn_mfma_f32_16x16x32_bf16(a, b0, acc0, 0, 0, 0);
                acc1 = __builtin_amdgcn_mfma_f32_16x16x32_bf16(a, b1, acc1, 0, 0, 0);
                acc2 = __builtin_amdgcn_mfma_f32_16x16x32_bf16(a, b2, acc2, 0, 0, 0);
                acc3 = __builtin_amdgcn_mfma_f32_16x16x32_bf16(a, b3, acc3, 0, 0, 0);
            }
            const int rbase = row0 + wave * 16 + quad * 4;
            #pragma unroll
            for (int cf = 0; cf < 4; ++cf) {
                const floatx4 av = (cf == 0) ? acc0 : (cf == 1) ? acc1 : (cf == 2) ? acc2 : acc3;
                const int col = ch * 64 + cf * 16 + l16;
                const float bv = bf2f(bias[col]);
                #pragma unroll
                for (int r = 0; r < 4; ++r) {
                    int row = rbase + r;
                    if (row < nrows) Y[(size_t)row * N + col] = f2bf(av[r] + bv);
                }
            }
        }
    }
}

// ---------------- fused layer-2 linear ------------------------------------
__global__ __launch_bounds__(256) void lin2_fused_kernel(
    const u16* __restrict__ X, const u16* __restrict__ Wt,   // Wt: [2][64][256]
    const u16* __restrict__ bl, const u16* __restrict__ br,
    u16* __restrict__ Yl, u16* __restrict__ Yr, int nrows)
{
    constexpr int K = 256, N = 64, LS = K + 8;
    __shared__ __align__(16) u16 sX[64 * LS];
    __shared__ __align__(16) u16 sW[64 * LS];
    const int row0 = blockIdx.x * 64;
    const int wave = threadIdx.x >> 6, lane = threadIdx.x & 63;
    const int quad = lane >> 4, l16 = lane & 15;

    for (int i = threadIdx.x * 8; i < 64 * K; i += 2048) {
        int r = i >> 8, c = i & 255;
        int gr = row0 + r;
        uint4 v = {0u, 0u, 0u, 0u};
        if (gr < nrows) v = *(const uint4*)&X[(size_t)gr * K + c];
        *(uint4*)&sX[r * LS + c] = v;
    }

    for (int side = 0; side < 2; ++side) {
        const u16* wbase = Wt + side * (N * K);
        const u16* bias  = side ? br : bl;
        u16* Y = side ? Yr : Yl;
        __syncthreads();
        for (int i = threadIdx.x * 8; i < 64 * K; i += 2048) {
            int n = i >> 8, c = i & 255;
            *(uint4*)&sW[n * LS + c] = *(const uint4*)&wbase[(size_t)n * K + c];
        }
        __syncthreads();
        floatx4 acc0 = {0.f, 0.f, 0.f, 0.f}, acc1 = acc0, acc2 = acc0, acc3 = acc0;
        #pragma unroll
        for (int kk = 0; kk < 8; ++kk) {
            short8 a  = *(const short8*)&sX[(wave * 16 + l16) * LS + kk * 32 + quad * 8];
            short8 b0 = *(const short8*)&sW[(l16) * LS + kk * 32 + quad * 8];
            short8 b1 = *(const short8*)&sW[(16 + l16) * LS + kk * 32 + quad * 8];
            short8 b2 = *(const short8*)&sW[(32 + l16) * LS + kk * 32 + quad * 8];
            short8 b3 = *(const short8*)&sW[(48 + l16) * LS + kk * 32 + quad * 8];
            acc0 = __builtin_amdgcn_mfma_f32_16x16x32_bf16(a, b0, acc0, 0, 0, 0);
            acc1 = __builtin_amdgcn_mfma_f32_16x16x32_bf16(a, b1, acc1, 0, 0, 0);
            acc2 = __builtin_amdgcn_mfma_f32_16x16x32_bf16(a, b2, acc2, 0, 0, 0);
            acc3 = __builtin_amdgcn_mfma_f32_16x16x32_bf16(a, b3, acc3, 0, 0, 0);
        }
        const int rbase = row0 + wave * 16 + quad * 4;
        #pragma unroll
        for (int cf = 0; cf < 4; ++cf) {
            const floatx4 av = (cf == 0) ? acc0 : (cf == 1) ? acc1 : (cf == 2) ? acc2 : acc3;
            const int col = cf * 16 + l16;
            const float bv = bf2f(bias[col]);
            #pragma unroll
            for (int r = 0; r < 4; ++r) {
                int row = rbase + r;
                if (row < nrows) Y[(size_t)row * N + col] = f2bf(av[r] + bv);
            }
        }
    }
}

// ---------------- layer 1 fused per-node GATv2 (4 heads x 64 ch) ------------
// R8 wave shape (lane l: head l>>4, channels [4l,4l+4), 4 edges/iter) with
// DPP reduces and packed-f32 (f32x2) score/acc math. leaky = max(t, 0.2t).
__global__ __launch_bounds__(256) void node1_kernel(
    const u16* __restrict__ xl, const u16* __restrict__ xr,
    const int* __restrict__ rowptr, const int* __restrict__ hist,
    const int* __restrict__ src_csr, const u16* __restrict__ att,
    const u16* __restrict__ bias, u16* __restrict__ hout)
{
    const int d = __builtin_amdgcn_readfirstlane(blockIdx.x * 4 + (threadIdx.x >> 6));
    if (d >= N_NODES) return;
    const int l = threadIdx.x & 63;
    const int start = rowptr[d];
    const int deg = hist[d];

    uint2 auv = *(const uint2*)&att[l * 4];
    const f32x2 atA = up2(auv.x), atB = up2(auv.y);
    uint2 ruv = *(const uint2*)&xr[(size_t)d * C1 + l * 4];
    const f32x2 rA = up2(ruv.x), rB = up2(ruv.y);

    float m = -1e30f, la = 0.f;
    f32x2 accA = {0.f, 0.f}, accB = {0.f, 0.f};
    for (int j = 0; j < deg; j += 4) {
        const bool v1 = j + 1 < deg, v2 = j + 2 < deg, v3 = j + 3 < deg;
        int s0 = src_csr[start + j];
        int s1 = v1 ? src_csr[start + j + 1] : s0;
        int s2 = v2 ? src_csr[start + j + 2] : s0;
        int s3 = v3 ? src_csr[start + j + 3] : s0;
        uint2 u0 = *(const uint2*)&xl[(size_t)s0 * C1 + l * 4];
        uint2 u1 = *(const uint2*)&xl[(size_t)s1 * C1 + l * 4];
        uint2 u2 = *(const uint2*)&xl[(size_t)s2 * C1 + l * 4];
        uint2 u3 = *(const uint2*)&xl[(size_t)s3 * C1 + l * 4];
        f32x2 x0A = up2(u0.x), x0B = up2(u0.y);
        f32x2 x1A = up2(u1.x), x1B = up2(u1.y);
        f32x2 x2A = up2(u2.x), x2B = up2(u2.y);
        f32x2 x3A = up2(u3.x), x3B = up2(u3.y);
        f32x2 t, pv;
        t = x0A + rA; t = __builtin_elementwise_max(t, t * SLOPE); pv  = t * atA;
        t = x0B + rB; t = __builtin_elementwise_max(t, t * SLOPE); pv += t * atB;
        float p0 = pv.x + pv.y;
        t = x1A + rA; t = __builtin_elementwise_max(t, t * SLOPE); pv  = t * atA;
        t = x1B + rB; t = __builtin_elementwise_max(t, t * SLOPE); pv += t * atB;
        float p1 = pv.x + pv.y;
        t = x2A + rA; t = __builtin_elementwise_max(t, t * SLOPE); pv  = t * atA;
        t = x2B + rB; t = __builtin_elementwise_max(t, t * SLOPE); pv += t * atB;
        float p2 = pv.x + pv.y;
        t = x3A + rA; t = __builtin_elementwise_max(t, t * SLOPE); pv  = t * atA;
        t = x3B + rB; t = __builtin_elementwise_max(t, t * SLOPE); pv += t * atB;
        float p3 = pv.x + pv.y;
        p0 = red16(p0); p1 = red16(p1); p2 = red16(p2); p3 = red16(p3);
        float pm = p0;
        if (v1) pm = fmaxf(pm, p1);
        if (v2) pm = fmaxf(pm, p2);
        if (v3) pm = fmaxf(pm, p3);
        float mn = fmaxf(m, pm);
        float sc = __expf(m - mn);
        float w0 = __expf(p0 - mn);
        float w1 = v1 ? __expf(p1 - mn) : 0.f;
        float w2 = v2 ? __expf(p2 - mn) : 0.f;
        float w3 = v3 ? __expf(p3 - mn) : 0.f;
        la = la * sc + w0 + w1 + w2 + w3;
        accA = accA * sc + x0A * w0 + x1A * w1 + x2A * w2 + x3A * w3;
        accB = accB * sc + x0B * w0 + x1B * w1 + x2B * w2 + x3B * w3;
        m = mn;
    }
    const float inv = 1.f / la;
    const int c = l * 4;
    float v0 = accA.x * inv + bf2f(bias[c + 0]);
    float v1 = accA.y * inv + bf2f(bias[c + 1]);
    float v2 = accB.x * inv + bf2f(bias[c + 2]);
    float v3 = accB.y * inv + bf2f(bias[c + 3]);
    v0 = v0 > 0.f ? v0 : __expf(fminf(v0, 0.f)) - 1.f;
    v1 = v1 > 0.f ? v1 : __expf(fminf(v1, 0.f)) - 1.f;
    v2 = v2 > 0.f ? v2 : __expf(fminf(v2, 0.f)) - 1.f;
    v3 = v3 > 0.f ? v3 : __expf(fminf(v3, 0.f)) - 1.f;
    ushort4 o;
    o.x = f2bf(v0); o.y = f2bf(v1); o.z = f2bf(v2); o.w = f2bf(v3);
    *(ushort4*)&hout[(size_t)d * C1 + c] = o;
}

// ---------------- layer 2 fused per-node GATv2 (1 head x 64 ch) --------------
// wave = 4x 16-lane groups, group g handles edge j+g; DPP group reduce,
// packed-f32 math.
__global__ __launch_bounds__(256) void node2_kernel(
    const u16* __restrict__ xl, const u16* __restrict__ xr,
    const int* __restrict__ rowptr, const int* __restrict__ hist,
    const int* __restrict__ src_csr, const u16* __restrict__ att,
    const u16* __restrict__ bias, void* __restrict__ outp,
    const int* __restrict__ cnt)
{
    const int d = __builtin_amdgcn_readfirstlane(blockIdx.x * 4 + (threadIdx.x >> 6));
    if (d >= N_NODES) return;
    const int l = threadIdx.x & 63;
    const int start = rowptr[d];
    const int deg = hist[d];
    const int g = l >> 4, sub = l & 15;
    const int c0 = sub * 4;

    uint2 auv = *(const uint2*)&att[c0];
    const f32x2 atA = up2(auv.x), atB = up2(auv.y);
    uint2 ruv = *(const uint2*)&xr[(size_t)d * OUTC + c0];
    const f32x2 rA = up2(ruv.x), rB = up2(ruv.y);

    float m = -1e30f, la = 0.f;
    f32x2 accA = {0.f, 0.f}, accB = {0.f, 0.f};
    for (int j = 0; j < deg; j += 4) {
        const bool valid = j + g < deg;
        int s = valid ? src_csr[start + j + g] : d;
        uint2 uv = *(const uint2*)&xl[(size_t)s * OUTC + c0];
        f32x2 xA = up2(uv.x), xB = up2(uv.y);
        f32x2 t, pv;
        t = xA + rA; t = __builtin_elementwise_max(t, t * SLOPE); pv  = t * atA;
        t = xB + rB; t = __builtin_elementwise_max(t, t * SLOPE); pv += t * atB;
        float p = pv.x + pv.y;
        p = red16(p);
        float pvv = valid ? p : -1e30f;
        float mn = fmaxf(m, pvv);
        float sc = __expf(m - mn);
        float w  = valid ? __expf(p - mn) : 0.f;
        la = la * sc + w;
        accA = accA * sc + xA * w;
        accB = accB * sc + xB * w;
        m = mn;
    }
    // merge the 4 groups' online-softmax states (xor 16, then 32)
    #pragma unroll
    for (int ofs = 16; ofs <= 32; ofs <<= 1) {
        float mo = __shfl_xor(m, ofs);
        float lo = __shfl_xor(la, ofs);
        float bax = __shfl_xor(accA.x, ofs);
        float bay = __shfl_xor(accA.y, ofs);
        float bbx = __shfl_xor(accB.x, ofs);
        float bby = __shfl_xor(accB.y, ofs);
        float mn = fmaxf(m, mo);
        float s0 = __expf(m - mn), s1 = __expf(mo - mn);
        la = la * s0 + lo * s1;
        accA.x = accA.x * s0 + bax * s1;
        accA.y = accA.y * s0 + bay * s1;
        accB.x = accB.x * s0 + bbx * s1;
        accB.y = accB.y * s0 + bby * s1;
        m = mn;
    }
    if (g == 0) {
        const float inv = 1.f / la;
        float v0 = accA.x * inv + bf2f(bias[c0 + 0]);
        float v1 = accA.y * inv + bf2f(bias[c0 + 1]);
        float v2 = accB.x * inv + bf2f(bias[c0 + 2]);
        float v3 = accB.y * inv + bf2f(bias[c0 + 3]);
        if (*cnt >= 32) {
            float4 o = make_float4(v0, v1, v2, v3);
            *(float4*)&((float*)outp)[(size_t)d * OUTC + c0] = o;
        } else {
            ushort4 o;
            o.x = f2bf(v0); o.y = f2bf(v1); o.z = f2bf(v2); o.w = f2bf(v3);
            *(ushort4*)&((u16*)outp)[(size_t)d * OUTC + c0] = o;
        }
    }
}

extern "C" void kernel_launch(void* const* d_in, const int* in_sizes, int n_in,
                              void* d_out, int out_size, void* d_ws, size_t ws_size,
                              hipStream_t stream)
{
    const void* x  = d_in[0];
    const int*  ei = (const int*)d_in[1];

    char* ws = (char*)d_ws;
    u16* xl1     = (u16*)(ws + 0);          // 25.6 MB
    u16* xr1     = (u16*)(ws + 25600000);   // 25.6 MB
    u16* hbuf    = (u16*)(ws + 51200000);   // 25.6 MB
    u16* xl2     = (u16*)(ws + 0);          // overlay xl1 (dead after node1)
    u16* xr2     = (u16*)(ws + 6400000);
    int* hist    = (int*)(ws + 76800000);
    int* rowptr  = (int*)(ws + 77000000);
    int* off     = (int*)(ws + 77200000);
    int* src_csr = (int*)(ws + 77400000);   // 1.8 MB
    int* cnt     = (int*)(ws + 79200000);
    u16* prm     = (u16*)(ws + 79200064);   // 1280 u16 small params
    u16* wt      = (u16*)(ws + 79210240);   // 98304 u16 transposed weights
    int* bsum    = (int*)(ws + 79410000);
    int* boff    = (int*)(ws + 79411024);

    u16* bl1   = prm + 0;
    u16* br1   = prm + 256;
    u16* att1  = prm + 512;
    u16* bias1 = prm + 768;
    u16* bl2   = prm + 1024;
    u16* br2   = prm + 1088;
    u16* att2  = prm + 1152;
    u16* bias2 = prm + 1216;
    u16* wt1   = wt + 0;       // [2][256][128]
    u16* wt2   = wt + 65536;   // [2][64][256]

    hipMemsetAsync(cnt, 0, 4, stream);
    detect_kernel<<<1, 256, 0, stream>>>((const unsigned*)x, cnt);
    convert_all_kernel<<<385, 256, 0, stream>>>(
        d_in[2], d_in[4], d_in[8], d_in[10],
        d_in[3], d_in[5], d_in[6], d_in[7], d_in[9], d_in[11], d_in[12], d_in[13],
        wt, prm, cnt);

    hipMemsetAsync(hist, 0, 200000, stream);
    const int eb = (ET + 255) / 256;
    hist_kernel<<<eb, 256, 0, stream>>>(ei, hist);
    scan1_kernel<<<196, 256, 0, stream>>>(hist, rowptr, bsum);
    scan2_kernel<<<1, 256, 0, stream>>>(bsum, boff);
    scan3_kernel<<<196, 256, 0, stream>>>(rowptr, boff, off);
    scatter_kernel<<<eb, 256, 0, stream>>>(ei, off, src_csr);

    const int gb = (N_NODES + 63) / 64;   // 782
    lin1_fused_kernel<<<gb, 256, 0, stream>>>((const u16*)x, wt1, bl1, br1, xl1, xr1, N_NODES, cnt);
    const int nb = (N_NODES * 64 + 255) / 256;   // 12500 blocks, 4 waves each
    node1_kernel<<<nb, 256, 0, stream>>>(xl1, xr1, rowptr, hist, src_csr, att1, bias1, hbuf);

    lin2_fused_kernel<<<gb, 256, 0, stream>>>(hbuf, wt2, bl2, br2, xl2, xr2, N_NODES);
    node2_kernel<<<nb, 256, 0, stream>>>(xl2, xr2, rowptr, hist, src_csr, att2, bias2, d_out, cnt);
}